// Round 1
// baseline (363.711 us; speedup 1.0000x reference)
//
#include <hip/hip_runtime.h>
#include <hip/hip_bf16.h>

typedef __bf16 bf16_t;
typedef __bf16 bf16x8 __attribute__((ext_vector_type(8)));
typedef __bf16 bf16x4 __attribute__((ext_vector_type(4)));
typedef float  floatx4 __attribute__((ext_vector_type(4)));

#define L2E 1.44269504088896340736f

static __device__ __forceinline__ floatx4 mfma16(bf16x8 a, bf16x8 b, floatx4 c) {
  return __builtin_amdgcn_mfma_f32_16x16x32_bf16(a, b, c, 0, 0, 0);
}

// ---------------- fp32 -> bf16 convert, 4 elems/thread ----------------
__global__ void cvt_kernel(const float* __restrict__ in, bf16_t* __restrict__ out, int n4) {
  int i = blockIdx.x * blockDim.x + threadIdx.x;
  if (i < n4) {
    float4 v = ((const float4*)in)[i];
    bf16x4 o;
    o[0] = (bf16_t)v.x; o[1] = (bf16_t)v.y; o[2] = (bf16_t)v.z; o[3] = (bf16_t)v.w;
    ((bf16x4*)out)[i] = o;
  }
}

// ---------------- NT GEMM: C(M,N) = A(M,K) * B(N,K)^T ----------------
// 128x128 tile, BK=32, 256 threads = 4 waves in 2x2, 16x16x32 bf16 MFMA.
// EPI==0: qkv scatter epilogue -> Q[bh][t][64], K[bh][t][64], Vt[bh][64][t] (bf16)
// EPI==1: plain fp32 store to Cf (row stride N)
template <int EPI>
__global__ __launch_bounds__(256) void gemm_nt(
    const bf16_t* __restrict__ A, const bf16_t* __restrict__ B,
    int M, int N, int K, float* __restrict__ Cf,
    bf16_t* __restrict__ Qo, bf16_t* __restrict__ Ko, bf16_t* __restrict__ Vto)
{
  __shared__ __align__(16) bf16_t As[128 * 32];
  __shared__ __align__(16) bf16_t Bs[128 * 32];
  const int tid  = threadIdx.x;
  const int lane = tid & 63;
  const int w    = tid >> 6;
  const int quad = lane >> 4;
  const int l15  = lane & 15;
  const int wm   = w & 1;
  const int wn   = w >> 1;
  const int bm   = blockIdx.x;
  const int bn   = blockIdx.y;

  floatx4 acc[4][4];
  #pragma unroll
  for (int i = 0; i < 4; ++i)
    #pragma unroll
    for (int j = 0; j < 4; ++j)
      acc[i][j] = (floatx4){0.f, 0.f, 0.f, 0.f};

  const bf16_t* Ab = A + (size_t)bm * 128 * K;
  const bf16_t* Bb = B + (size_t)bn * 128 * K;

  for (int k0 = 0; k0 < K; k0 += 32) {
    __syncthreads();
    #pragma unroll
    for (int i = 0; i < 2; ++i) {
      int c = tid + 256 * i;            // 0..511 : 16B chunks of the 8KB tile
      int row = c >> 2, col = (c & 3) << 3;
      *(uint4*)&As[row * 32 + col] = *(const uint4*)&Ab[(size_t)row * K + k0 + col];
      *(uint4*)&Bs[row * 32 + col] = *(const uint4*)&Bb[(size_t)row * K + k0 + col];
    }
    __syncthreads();
    bf16x8 af[4], bfr[4];
    #pragma unroll
    for (int t = 0; t < 4; ++t) {
      af[t]  = *(const bf16x8*)&As[(wm * 64 + t * 16 + l15) * 32 + quad * 8];
      bfr[t] = *(const bf16x8*)&Bs[(wn * 64 + t * 16 + l15) * 32 + quad * 8];
    }
    #pragma unroll
    for (int mt = 0; mt < 4; ++mt)
      #pragma unroll
      for (int nt = 0; nt < 4; ++nt)
        acc[mt][nt] = mfma16(af[mt], bfr[nt], acc[mt][nt]);
  }

  #pragma unroll
  for (int mt = 0; mt < 4; ++mt) {
    #pragma unroll
    for (int nt = 0; nt < 4; ++nt) {
      #pragma unroll
      for (int r = 0; r < 4; ++r) {
        int m = bm * 128 + wm * 64 + mt * 16 + quad * 4 + r;
        int n = bn * 128 + wn * 64 + nt * 16 + l15;
        float v = acc[mt][nt][r];
        if (EPI == 1) {
          Cf[(size_t)m * N + n] = v;
        } else {
          int b = m >> 12, t = m & 4095;
          int which = n >> 9, h = (n >> 6) & 7, d = n & 63;   // which uniform per block
          size_t bh = (size_t)(b * 8 + h);
          bf16_t bv = (bf16_t)v;
          if (which == 0)
            Qo[bh * 262144 + (size_t)t * 64 + d] = bv;
          else if (which == 1)
            Ko[bh * 262144 + (size_t)t * 64 + d] = bv;
          else
            Vto[bh * 262144 + (size_t)d * 4096 + t] = bv;     // V stored transposed
        }
      }
    }
  }
}

// ---------------- causal flash attention ----------------
// grid (16, 16): x -> paired q-tiles {x, 31-x} (uniform 33 k-iters), y -> bh.
// 256 threads = 4 waves; wave w owns q-rows [w*32, w*32+32) of the 128-row tile.
// LDS: Qs 16K + Ks 16K + Vts 16K + Ps 16K = 64KB. XOR chunk swizzle vs conflicts.
__global__ __launch_bounds__(256) void attn_kernel(
    const bf16_t* __restrict__ Qg, const bf16_t* __restrict__ Kgl,
    const bf16_t* __restrict__ Vtg, bf16_t* __restrict__ Og)
{
  __shared__ __align__(16) bf16_t Qs[128 * 64];
  __shared__ __align__(16) bf16_t Ks[128 * 64];
  __shared__ __align__(16) bf16_t Vts[64 * 128];
  __shared__ __align__(16) bf16_t Ps[4][32 * 64];

  const int tid  = threadIdx.x;
  const int lane = tid & 63;
  const int w    = tid >> 6;
  const int quad = lane >> 4;
  const int l15  = lane & 15;
  const int l7   = lane & 7;
  const int bx   = blockIdx.x;   // 0..15
  const int bh   = blockIdx.y;   // 0..15
  const size_t bh_off = (size_t)bh * 262144;

  for (int phase = 0; phase < 2; ++phase) {
    const int qt = phase ? (31 - bx) : bx;
    __syncthreads();   // all waves done with previous phase before restaging Qs
    {
      const bf16_t* Qp = Qg + bh_off + (size_t)qt * 8192;
      #pragma unroll
      for (int i = 0; i < 4; ++i) {
        int c = tid + 256 * i;
        int row = c >> 3, col = c & 7;
        *(uint4*)&Qs[row * 64 + ((col ^ (row & 7)) << 3)] =
            *(const uint4*)&Qp[row * 64 + (col << 3)];
      }
    }
    floatx4 acc_o[2][4];
    float mst[2][4], lst[2][4];
    #pragma unroll
    for (int mt = 0; mt < 2; ++mt) {
      #pragma unroll
      for (int dt = 0; dt < 4; ++dt) acc_o[mt][dt] = (floatx4){0.f, 0.f, 0.f, 0.f};
      #pragma unroll
      for (int r = 0; r < 4; ++r) { mst[mt][r] = -3.0e38f; lst[mt][r] = 0.f; }
    }

    for (int kt = 0; kt <= qt; ++kt) {
      __syncthreads();   // prev iter's PV reads done; Qs staging visible on kt==0
      {
        const bf16_t* Kp = Kgl + bh_off + (size_t)kt * 8192;
        const bf16_t* Vp = Vtg + bh_off + (size_t)kt * 128;
        #pragma unroll
        for (int i = 0; i < 4; ++i) {
          int c = tid + 256 * i;
          int row = c >> 3, col = c & 7;
          *(uint4*)&Ks[row * 64 + ((col ^ (row & 7)) << 3)] =
              *(const uint4*)&Kp[row * 64 + (col << 3)];
        }
        #pragma unroll
        for (int i = 0; i < 4; ++i) {
          int c = tid + 256 * i;
          int row = c >> 4, col = c & 15;
          *(uint4*)&Vts[row * 128 + ((col ^ (row & 15)) << 3)] =
              *(const uint4*)&Vp[(size_t)row * 4096 + (col << 3)];
        }
      }
      __syncthreads();

      // ---- S = Q K^T (per wave: 32 x 128), K-dim 64 in 2 MFMA steps ----
      floatx4 s[2][8];
      #pragma unroll
      for (int mt = 0; mt < 2; ++mt)
        #pragma unroll
        for (int nt = 0; nt < 8; ++nt) s[mt][nt] = (floatx4){0.f, 0.f, 0.f, 0.f};

      #pragma unroll
      for (int ks = 0; ks < 2; ++ks) {
        bf16x8 aq[2], bk[8];
        #pragma unroll
        for (int mt = 0; mt < 2; ++mt)
          aq[mt] = *(const bf16x8*)&Qs[(w * 32 + mt * 16 + l15) * 64 +
                                       (((ks * 4 + quad) ^ l7) << 3)];
        #pragma unroll
        for (int nt = 0; nt < 8; ++nt)
          bk[nt] = *(const bf16x8*)&Ks[(nt * 16 + l15) * 64 +
                                       (((ks * 4 + quad) ^ l7) << 3)];
        #pragma unroll
        for (int mt = 0; mt < 2; ++mt)
          #pragma unroll
          for (int nt = 0; nt < 8; ++nt)
            s[mt][nt] = mfma16(aq[mt], bk[nt], s[mt][nt]);
      }

      // ---- online softmax (C-layout: row = quad*4+r, col = l15) ----
      const bool diag = (kt == qt);
      float alpha_v[2][4];
      #pragma unroll
      for (int mt = 0; mt < 2; ++mt) {
        #pragma unroll
        for (int r = 0; r < 4; ++r) {
          const int qrow_l = w * 32 + mt * 16 + quad * 4 + r;
          float mx = -3.0e38f;
          #pragma unroll
          for (int nt = 0; nt < 8; ++nt) {
            float sv = s[mt][nt][r] * 0.125f;
            if (diag && (nt * 16 + l15 > qrow_l)) sv = -3.0e38f;
            s[mt][nt][r] = sv;
            mx = fmaxf(mx, sv);
          }
          mx = fmaxf(mx, __shfl_xor(mx, 1));
          mx = fmaxf(mx, __shfl_xor(mx, 2));
          mx = fmaxf(mx, __shfl_xor(mx, 4));
          mx = fmaxf(mx, __shfl_xor(mx, 8));
          float mnew  = fmaxf(mst[mt][r], mx);
          float alpha = exp2f((mst[mt][r] - mnew) * L2E);
          mst[mt][r] = mnew;
          float sum = 0.f;
          #pragma unroll
          for (int nt = 0; nt < 8; ++nt) {
            float p = exp2f((s[mt][nt][r] - mnew) * L2E);
            s[mt][nt][r] = p;
            sum += p;
          }
          sum += __shfl_xor(sum, 1);
          sum += __shfl_xor(sum, 2);
          sum += __shfl_xor(sum, 4);
          sum += __shfl_xor(sum, 8);
          lst[mt][r] = lst[mt][r] * alpha + sum;
          alpha_v[mt][r] = alpha;
        }
      }
      #pragma unroll
      for (int mt = 0; mt < 2; ++mt)
        #pragma unroll
        for (int dt = 0; dt < 4; ++dt)
          #pragma unroll
          for (int r = 0; r < 4; ++r)
            acc_o[mt][dt][r] *= alpha_v[mt][r];

      // ---- PV: O += P V, in two 64-col halves via per-wave Ps (LDS) ----
      #pragma unroll
      for (int hf = 0; hf < 2; ++hf) {
        #pragma unroll
        for (int mt = 0; mt < 2; ++mt)
          #pragma unroll
          for (int nt4 = 0; nt4 < 4; ++nt4)
            #pragma unroll
            for (int r = 0; r < 4; ++r) {
              int row = mt * 16 + quad * 4 + r;
              int chunk = nt4 * 2 + (l15 >> 3);
              Ps[w][row * 64 + ((chunk ^ (row & 7)) << 3) + l7] =
                  (bf16_t)s[mt][hf * 4 + nt4][r];
            }
        #pragma unroll
        for (int ksl = 0; ksl < 2; ++ksl) {
          const int ks = hf * 2 + ksl;
          bf16x8 ap[2], bv[4];
          #pragma unroll
          for (int mt = 0; mt < 2; ++mt)
            ap[mt] = *(const bf16x8*)&Ps[w][(mt * 16 + l15) * 64 +
                                            (((ksl * 4 + quad) ^ l7) << 3)];
          #pragma unroll
          for (int dt = 0; dt < 4; ++dt)
            bv[dt] = *(const bf16x8*)&Vts[(dt * 16 + l15) * 128 +
                                          (((ks * 4 + quad) ^ l15) << 3)];
          #pragma unroll
          for (int mt = 0; mt < 2; ++mt)
            #pragma unroll
            for (int dt = 0; dt < 4; ++dt)
              acc_o[mt][dt] = mfma16(ap[mt], bv[dt], acc_o[mt][dt]);
        }
      }
    }

    // ---- epilogue: normalize and store O tile into (B*T, 512) bf16 ----
    {
      const int b = bh >> 3, h = bh & 7;
      #pragma unroll
      for (int mt = 0; mt < 2; ++mt)
        #pragma unroll
        for (int dt = 0; dt < 4; ++dt)
          #pragma unroll
          for (int r = 0; r < 4; ++r) {
            int trow = qt * 128 + w * 32 + mt * 16 + quad * 4 + r;
            float ov = acc_o[mt][dt][r] / lst[mt][r];
            Og[((size_t)b * 4096 + trow) * 512 + h * 64 + dt * 16 + l15] = (bf16_t)ov;
          }
    }
  }
}

// ---------------- launcher ----------------
extern "C" void kernel_launch(void* const* d_in, const int* in_sizes, int n_in,
                              void* d_out, int out_size, void* d_ws, size_t ws_size,
                              hipStream_t stream) {
  const float* x    = (const float*)d_in[0];   // (2,4096,512)
  const float* wqkv = (const float*)d_in[1];   // (1536,512)
  const float* wo   = (const float*)d_in[2];   // (512,512)
  float* out = (float*)d_out;                  // (2,4096,512) fp32

  char* ws = (char*)d_ws;
  bf16_t* xb    = (bf16_t*)(ws);                 //  8 MB  x bf16
  bf16_t* wqkvb = (bf16_t*)(ws + 8388608);       //  1.5 MB
  bf16_t* wob   = (bf16_t*)(ws + 9961472);       //  0.5 MB
  bf16_t* Qb    = (bf16_t*)(ws + 10485760);      //  8 MB  [bh][t][64]
  bf16_t* Kb    = (bf16_t*)(ws + 18874368);      //  8 MB  [bh][t][64]
  bf16_t* Vtb   = (bf16_t*)(ws + 27262976);      //  8 MB  [bh][64][t]
  bf16_t* Ob    = (bf16_t*)(ws + 35651584);      //  8 MB  (B*T, 512)
  // total 44,040,192 bytes

  cvt_kernel<<<4096, 256, 0, stream>>>(x,    xb,    1048576);
  cvt_kernel<<<768,  256, 0, stream>>>(wqkv, wqkvb, 196608);
  cvt_kernel<<<256,  256, 0, stream>>>(wo,   wob,   65536);

  gemm_nt<0><<<dim3(64, 12), 256, 0, stream>>>(xb, wqkvb, 8192, 1536, 512,
                                               nullptr, Qb, Kb, Vtb);
  attn_kernel<<<dim3(16, 16), 256, 0, stream>>>(Qb, Kb, Vtb, Ob);
  gemm_nt<1><<<dim3(64, 4), 256, 0, stream>>>(Ob, wob, 8192, 512, 512,
                                              out, nullptr, nullptr, nullptr);
}

// Round 2
// 298.248 us; speedup vs baseline: 1.2195x; 1.2195x over previous
//
#include <hip/hip_runtime.h>
#include <hip/hip_bf16.h>

typedef __bf16 bf16_t;
typedef __bf16 bf16x8 __attribute__((ext_vector_type(8)));
typedef __bf16 bf16x4 __attribute__((ext_vector_type(4)));
typedef float  floatx4 __attribute__((ext_vector_type(4)));

#define L2E 1.44269504088896340736f

static __device__ __forceinline__ floatx4 mfma16(bf16x8 a, bf16x8 b, floatx4 c) {
  return __builtin_amdgcn_mfma_f32_16x16x32_bf16(a, b, c, 0, 0, 0);
}

// async global->LDS, 16B per lane. LDS dest must be wave-uniform base + lane*16,
// which all call sites satisfy (chunk index c = w*64 + lane + 256*i, LDS addr c*16B).
typedef __attribute__((address_space(3))) void lds_vp;
typedef __attribute__((address_space(1))) void glb_vp;
#define GLDS16(g, l) \
  __builtin_amdgcn_global_load_lds((glb_vp*)(g), (lds_vp*)(l), 16, 0, 0)

// ---------------- fp32 -> bf16 convert, 4 elems/thread ----------------
__global__ void cvt_kernel(const float* __restrict__ in, bf16_t* __restrict__ out, int n4) {
  int i = blockIdx.x * blockDim.x + threadIdx.x;
  if (i < n4) {
    float4 v = ((const float4*)in)[i];
    bf16x4 o;
    o[0] = (bf16_t)v.x; o[1] = (bf16_t)v.y; o[2] = (bf16_t)v.z; o[3] = (bf16_t)v.w;
    ((bf16x4*)out)[i] = o;
  }
}

// ---------------- NT GEMM: C(M,N) = A(M,K) * B(N,K)^T ----------------
// 128x128 tile, BK=64, 4 waves 2x2, global_load_lds staging with XOR gather-
// swizzle (LDS stays lane-contiguous; global column chunk is permuted so the
// LDS layout ends up swizzled -> conflict-free ds_read_b128 per 16-lane phase).
// EPI==0: qkv scatter -> Q*0.125 [bh][t][64], K [bh][t][64], Vt [bh][64][t]
// EPI==1: plain fp32 store
template <int EPI>
__global__ __launch_bounds__(256) void gemm_nt(
    const bf16_t* __restrict__ A, const bf16_t* __restrict__ B,
    int M, int N, int K, float* __restrict__ Cf,
    bf16_t* __restrict__ Qo, bf16_t* __restrict__ Ko, bf16_t* __restrict__ Vto)
{
  __shared__ __align__(16) bf16_t As[128 * 64];
  __shared__ __align__(16) bf16_t Bs[128 * 64];
  const int tid  = threadIdx.x;
  const int lane = tid & 63;
  const int w    = tid >> 6;
  const int quad = lane >> 4;
  const int l15  = lane & 15;
  const int l7   = lane & 7;
  const int wm   = w & 1;
  const int wn   = w >> 1;

  floatx4 acc[4][4];
  #pragma unroll
  for (int i = 0; i < 4; ++i)
    #pragma unroll
    for (int j = 0; j < 4; ++j)
      acc[i][j] = (floatx4){0.f, 0.f, 0.f, 0.f};

  const bf16_t* Ab = A + (size_t)blockIdx.x * 128 * K;
  const bf16_t* Bb = B + (size_t)blockIdx.y * 128 * K;

  for (int k0 = 0; k0 < K; k0 += 64) {
    __syncthreads();
    #pragma unroll
    for (int i = 0; i < 4; ++i) {
      int c = w * 64 + lane + 256 * i;          // 0..1023 chunk of 16B
      int row = c >> 3, colc = c & 7;
      int gofs = ((colc ^ (row & 7)) << 3);     // gather-swizzle within the 128B row
      GLDS16(&Ab[(size_t)row * K + k0 + gofs], &As[c * 8]);
      GLDS16(&Bb[(size_t)row * K + k0 + gofs], &Bs[c * 8]);
    }
    __syncthreads();
    #pragma unroll
    for (int ks = 0; ks < 2; ++ks) {
      bf16x8 af[4], bfr[4];
      #pragma unroll
      for (int t = 0; t < 4; ++t) {
        af[t]  = *(const bf16x8*)&As[(wm * 64 + t * 16 + l15) * 64 +
                                     (((ks * 4 + quad) ^ l7) << 3)];
        bfr[t] = *(const bf16x8*)&Bs[(wn * 64 + t * 16 + l15) * 64 +
                                     (((ks * 4 + quad) ^ l7) << 3)];
      }
      #pragma unroll
      for (int mt = 0; mt < 4; ++mt)
        #pragma unroll
        for (int nt = 0; nt < 4; ++nt)
          acc[mt][nt] = mfma16(af[mt], bfr[nt], acc[mt][nt]);
    }
  }

  #pragma unroll
  for (int mt = 0; mt < 4; ++mt) {
    #pragma unroll
    for (int nt = 0; nt < 4; ++nt) {
      #pragma unroll
      for (int r = 0; r < 4; ++r) {
        int m = blockIdx.x * 128 + wm * 64 + mt * 16 + quad * 4 + r;
        int n = blockIdx.y * 128 + wn * 64 + nt * 16 + l15;
        float v = acc[mt][nt][r];
        if (EPI == 1) {
          Cf[(size_t)m * N + n] = v;
        } else {
          int b = m >> 12, t = m & 4095;
          int which = n >> 9, h = (n >> 6) & 7, d = n & 63;  // uniform per block
          size_t bh = (size_t)(b * 8 + h);
          if (which == 0)
            Qo[bh * 262144 + (size_t)t * 64 + d] = (bf16_t)(v * 0.125f);  // fold 1/sqrt(64)
          else if (which == 1)
            Ko[bh * 262144 + (size_t)t * 64 + d] = (bf16_t)v;
          else
            Vto[bh * 262144 + (size_t)d * 4096 + t] = (bf16_t)v;          // V transposed
        }
      }
    }
  }
}

// ---------------- causal flash attention ----------------
// grid (64, 16): x -> q-tile (64 rows, reversed so big blocks dispatch first),
// y -> bh. 256 threads = 4 waves; wave w owns q-rows [w*16, w*16+16).
// k-tiles 128 wide, nkt = qt/2+1. LDS 48KB -> 3 blocks/CU = 12 waves/CU.
__global__ __launch_bounds__(256, 3) void attn_kernel(
    const bf16_t* __restrict__ Qg, const bf16_t* __restrict__ Kgl,
    const bf16_t* __restrict__ Vtg, bf16_t* __restrict__ Og)
{
  __shared__ __align__(16) bf16_t Qs[64 * 64];
  __shared__ __align__(16) bf16_t Ks[128 * 64];
  __shared__ __align__(16) bf16_t Vts[64 * 128];
  __shared__ __align__(16) bf16_t Ps[4][16 * 64];

  const int tid  = threadIdx.x;
  const int lane = tid & 63;
  const int w    = tid >> 6;
  const int quad = lane >> 4;
  const int l15  = lane & 15;
  const int l7   = lane & 7;
  const int qt   = 63 - blockIdx.x;            // big (many-iter) blocks first
  const int bh   = blockIdx.y;
  const size_t bh_off = (size_t)bh * 262144;
  const int b = bh >> 3, h = bh & 7;

  // stage Q tile (64x64) once
  {
    const bf16_t* Qp = Qg + bh_off + (size_t)qt * 4096;
    #pragma unroll
    for (int i = 0; i < 2; ++i) {
      int c = w * 64 + lane + 256 * i;          // 0..511
      int row = c >> 3, colc = c & 7;
      GLDS16(&Qp[row * 64 + ((colc ^ (row & 7)) << 3)], &Qs[c * 8]);
    }
  }

  floatx4 acc_o[4];
  float mst[4], lst[4];
  #pragma unroll
  for (int dt = 0; dt < 4; ++dt) acc_o[dt] = (floatx4){0.f, 0.f, 0.f, 0.f};
  #pragma unroll
  for (int r = 0; r < 4; ++r) { mst[r] = -3.0e38f; lst[r] = 0.f; }

  const int nkt = (qt >> 1) + 1;
  for (int kt = 0; kt < nkt; ++kt) {
    __syncthreads();   // prev iter's LDS reads done (also covers Q staging drain)
    {
      const bf16_t* Kp = Kgl + bh_off + (size_t)kt * 8192;
      const bf16_t* Vp = Vtg + bh_off + (size_t)kt * 128;
      #pragma unroll
      for (int i = 0; i < 4; ++i) {
        int c = w * 64 + lane + 256 * i;        // 0..1023
        int row = c >> 3, colc = c & 7;
        GLDS16(&Kp[row * 64 + ((colc ^ (row & 7)) << 3)], &Ks[c * 8]);
      }
      #pragma unroll
      for (int i = 0; i < 4; ++i) {
        int c = w * 64 + lane + 256 * i;
        int row = c >> 4, colc = c & 15;
        GLDS16(&Vp[(size_t)row * 4096 + ((colc ^ (row & 15)) << 3)], &Vts[c * 8]);
      }
    }
    __syncthreads();

    // ---- S = Q K^T : 16 x 128 per wave ----
    floatx4 s[8];
    #pragma unroll
    for (int nt = 0; nt < 8; ++nt) s[nt] = (floatx4){0.f, 0.f, 0.f, 0.f};
    #pragma unroll
    for (int ks = 0; ks < 2; ++ks) {
      bf16x8 aq = *(const bf16x8*)&Qs[(w * 16 + l15) * 64 +
                                      (((ks * 4 + quad) ^ l7) << 3)];
      #pragma unroll
      for (int nt = 0; nt < 8; ++nt) {
        bf16x8 bk = *(const bf16x8*)&Ks[(nt * 16 + l15) * 64 +
                                        (((ks * 4 + quad) ^ l7) << 3)];
        s[nt] = mfma16(aq, bk, s[nt]);
      }
    }

    // ---- online softmax (Q pre-scaled; C-layout row=quad*4+r, col=l15) ----
    const bool diag = (kt == (qt >> 1));
    float alpha_v[4];
    #pragma unroll
    for (int r = 0; r < 4; ++r) {
      const int grow  = qt * 64 + w * 16 + quad * 4 + r;
      const int gcol0 = kt * 128 + l15;
      float mx = -3.0e38f;
      #pragma unroll
      for (int nt = 0; nt < 8; ++nt) {
        float sv = s[nt][r];
        if (diag && (gcol0 + nt * 16 > grow)) sv = -3.0e38f;
        s[nt][r] = sv;
        mx = fmaxf(mx, sv);
      }
      mx = fmaxf(mx, __shfl_xor(mx, 1));
      mx = fmaxf(mx, __shfl_xor(mx, 2));
      mx = fmaxf(mx, __shfl_xor(mx, 4));
      mx = fmaxf(mx, __shfl_xor(mx, 8));
      float mnew  = fmaxf(mst[r], mx);
      float alpha = exp2f((mst[r] - mnew) * L2E);
      mst[r] = mnew;
      float sum = 0.f;
      #pragma unroll
      for (int nt = 0; nt < 8; ++nt) {
        float p = exp2f((s[nt][r] - mnew) * L2E);
        s[nt][r] = p;
        sum += p;
      }
      sum += __shfl_xor(sum, 1);
      sum += __shfl_xor(sum, 2);
      sum += __shfl_xor(sum, 4);
      sum += __shfl_xor(sum, 8);
      lst[r] = lst[r] * alpha + sum;
      alpha_v[r] = alpha;
    }
    #pragma unroll
    for (int dt = 0; dt < 4; ++dt)
      #pragma unroll
      for (int r = 0; r < 4; ++r)
        acc_o[dt][r] *= alpha_v[r];

    // ---- PV: O += P V in two 64-col halves via per-wave Ps ----
    #pragma unroll
    for (int hf = 0; hf < 2; ++hf) {
      #pragma unroll
      for (int nt4 = 0; nt4 < 4; ++nt4)
        #pragma unroll
        for (int r = 0; r < 4; ++r) {
          int row = quad * 4 + r;
          int chunk = nt4 * 2 + (l15 >> 3);
          Ps[w][row * 64 + ((chunk ^ (row & 7)) << 3) + l7] =
              (bf16_t)s[hf * 4 + nt4][r];
        }
      #pragma unroll
      for (int ksl = 0; ksl < 2; ++ksl) {
        bf16x8 ap = *(const bf16x8*)&Ps[w][l15 * 64 +
                                          (((ksl * 4 + quad) ^ l7) << 3)];
        #pragma unroll
        for (int dt = 0; dt < 4; ++dt) {
          bf16x8 bv = *(const bf16x8*)&Vts[(dt * 16 + l15) * 128 +
                                           ((((hf * 2 + ksl) * 4 + quad) ^ l15) << 3)];
          acc_o[dt] = mfma16(ap, bv, acc_o[dt]);
        }
      }
    }
  }

  // ---- epilogue: normalize, store O tile into (B*T, 512) bf16 ----
  #pragma unroll
  for (int dt = 0; dt < 4; ++dt)
    #pragma unroll
    for (int r = 0; r < 4; ++r) {
      int trow = qt * 64 + w * 16 + quad * 4 + r;
      float ov = acc_o[dt][r] / lst[r];
      Og[((size_t)b * 4096 + trow) * 512 + h * 64 + dt * 16 + l15] = (bf16_t)ov;
    }
}

// ---------------- launcher ----------------
extern "C" void kernel_launch(void* const* d_in, const int* in_sizes, int n_in,
                              void* d_out, int out_size, void* d_ws, size_t ws_size,
                              hipStream_t stream) {
  const float* x    = (const float*)d_in[0];   // (2,4096,512)
  const float* wqkv = (const float*)d_in[1];   // (1536,512)
  const float* wo   = (const float*)d_in[2];   // (512,512)
  float* out = (float*)d_out;                  // (2,4096,512) fp32

  char* ws = (char*)d_ws;
  bf16_t* xb    = (bf16_t*)(ws);                 //  8 MB
  bf16_t* wqkvb = (bf16_t*)(ws + 8388608);       //  1.5 MB
  bf16_t* wob   = (bf16_t*)(ws + 9961472);       //  0.5 MB
  bf16_t* Qb    = (bf16_t*)(ws + 10485760);      //  8 MB  [bh][t][64], pre-scaled
  bf16_t* Kb    = (bf16_t*)(ws + 18874368);      //  8 MB  [bh][t][64]
  bf16_t* Vtb   = (bf16_t*)(ws + 27262976);      //  8 MB  [bh][64][t]
  bf16_t* Ob    = (bf16_t*)(ws + 35651584);      //  8 MB  (B*T, 512)
  // total 44,040,192 bytes

  cvt_kernel<<<4096, 256, 0, stream>>>(x,    xb,    1048576);
  cvt_kernel<<<768,  256, 0, stream>>>(wqkv, wqkvb, 196608);
  cvt_kernel<<<256,  256, 0, stream>>>(wo,   wob,   65536);

  gemm_nt<0><<<dim3(64, 12), 256, 0, stream>>>(xb, wqkvb, 8192, 1536, 512,
                                               nullptr, Qb, Kb, Vtb);
  attn_kernel<<<dim3(64, 16), 256, 0, stream>>>(Qb, Kb, Vtb, Ob);
  gemm_nt<1><<<dim3(64, 4), 256, 0, stream>>>(Ob, wob, 8192, 512, 512,
                                              out, nullptr, nullptr, nullptr);
}

// Round 3
// 226.617 us; speedup vs baseline: 1.6050x; 1.3161x over previous
//
#include <hip/hip_runtime.h>
#include <hip/hip_bf16.h>

typedef __bf16 bf16_t;
typedef __bf16 bf16x8 __attribute__((ext_vector_type(8)));
typedef __bf16 bf16x4 __attribute__((ext_vector_type(4)));
typedef float  floatx4 __attribute__((ext_vector_type(4)));

#define L2E 1.44269504088896340736f

static __device__ __forceinline__ floatx4 mfma16(bf16x8 a, bf16x8 b, floatx4 c) {
  return __builtin_amdgcn_mfma_f32_16x16x32_bf16(a, b, c, 0, 0, 0);
}

// async global->LDS, 16B per lane; LDS dest = wave-uniform base + lane*16.
typedef __attribute__((address_space(3))) void lds_vp;
typedef __attribute__((address_space(1))) void glb_vp;
#define GLDS16(g, l) \
  __builtin_amdgcn_global_load_lds((glb_vp*)(g), (lds_vp*)(l), 16, 0, 0)

// ---------------- fp32 -> bf16 convert, 4 elems/thread ----------------
__global__ void cvt_kernel(const float* __restrict__ in, bf16_t* __restrict__ out, int n4) {
  int i = blockIdx.x * blockDim.x + threadIdx.x;
  if (i < n4) {
    float4 v = ((const float4*)in)[i];
    bf16x4 o;
    o[0] = (bf16_t)v.x; o[1] = (bf16_t)v.y; o[2] = (bf16_t)v.z; o[3] = (bf16_t)v.w;
    ((bf16x4*)out)[i] = o;
  }
}

// ---------------- NT GEMM: C(M,N) = A(M,K) * B(N,K)^T ---------------- (unchanged, passing)
template <int EPI>
__global__ __launch_bounds__(256) void gemm_nt(
    const bf16_t* __restrict__ A, const bf16_t* __restrict__ B,
    int M, int N, int K, float* __restrict__ Cf,
    bf16_t* __restrict__ Qo, bf16_t* __restrict__ Ko, bf16_t* __restrict__ Vto)
{
  __shared__ __align__(16) bf16_t As[128 * 64];
  __shared__ __align__(16) bf16_t Bs[128 * 64];
  const int tid  = threadIdx.x;
  const int lane = tid & 63;
  const int w    = tid >> 6;
  const int quad = lane >> 4;
  const int l15  = lane & 15;
  const int l7   = lane & 7;
  const int wm   = w & 1;
  const int wn   = w >> 1;

  floatx4 acc[4][4];
  #pragma unroll
  for (int i = 0; i < 4; ++i)
    #pragma unroll
    for (int j = 0; j < 4; ++j)
      acc[i][j] = (floatx4){0.f, 0.f, 0.f, 0.f};

  const bf16_t* Ab = A + (size_t)blockIdx.x * 128 * K;
  const bf16_t* Bb = B + (size_t)blockIdx.y * 128 * K;

  for (int k0 = 0; k0 < K; k0 += 64) {
    __syncthreads();
    #pragma unroll
    for (int i = 0; i < 4; ++i) {
      int c = tid + 256 * i;
      int row = c >> 3, colc = c & 7;
      int gofs = ((colc ^ (row & 7)) << 3);
      GLDS16(&Ab[(size_t)row * K + k0 + gofs], &As[c * 8]);
      GLDS16(&Bb[(size_t)row * K + k0 + gofs], &Bs[c * 8]);
    }
    __syncthreads();
    #pragma unroll
    for (int ks = 0; ks < 2; ++ks) {
      bf16x8 af[4], bfr[4];
      #pragma unroll
      for (int t = 0; t < 4; ++t) {
        af[t]  = *(const bf16x8*)&As[(wm * 64 + t * 16 + l15) * 64 +
                                     (((ks * 4 + quad) ^ l7) << 3)];
        bfr[t] = *(const bf16x8*)&Bs[(wn * 64 + t * 16 + l15) * 64 +
                                     (((ks * 4 + quad) ^ l7) << 3)];
      }
      #pragma unroll
      for (int mt = 0; mt < 4; ++mt)
        #pragma unroll
        for (int nt = 0; nt < 4; ++nt)
          acc[mt][nt] = mfma16(af[mt], bfr[nt], acc[mt][nt]);
    }
  }

  #pragma unroll
  for (int mt = 0; mt < 4; ++mt) {
    #pragma unroll
    for (int nt = 0; nt < 4; ++nt) {
      #pragma unroll
      for (int r = 0; r < 4; ++r) {
        int m = blockIdx.x * 128 + wm * 64 + mt * 16 + quad * 4 + r;
        int n = blockIdx.y * 128 + wn * 64 + nt * 16 + l15;
        float v = acc[mt][nt][r];
        if (EPI == 1) {
          Cf[(size_t)m * N + n] = v;
        } else {
          int b = m >> 12, t = m & 4095;
          int which = n >> 9, h = (n >> 6) & 7, d = n & 63;
          size_t bh = (size_t)(b * 8 + h);
          if (which == 0)
            Qo[bh * 262144 + (size_t)t * 64 + d] = (bf16_t)(v * 0.125f);
          else if (which == 1)
            Ko[bh * 262144 + (size_t)t * 64 + d] = (bf16_t)v;
          else
            Vto[bh * 262144 + (size_t)d * 4096 + t] = (bf16_t)v;
        }
      }
    }
  }
}

// ---------------- causal flash attention, S^T formulation ----------------
// grid (64,16): qt = (x + 4y) & 63 (mixes sizes within any 256-block window).
// Per wave: 16 q-rows (q = w*16 + l15, one q per lane), k-tile 128 wide.
// S^T = K·Q^T -> softmax in-lane + 2 shfl -> P^T feeds PV directly as B-operand.
// LDS: Ks 16K + Vts 16K = 32KB; O^T transposed out through Ks at the end.
__global__ __launch_bounds__(256, 4) void attn_kernel(
    const bf16_t* __restrict__ Qg, const bf16_t* __restrict__ Kgl,
    const bf16_t* __restrict__ Vtg, bf16_t* __restrict__ Og)
{
  __shared__ __align__(16) bf16_t Ks[128 * 64];
  __shared__ __align__(16) bf16_t Vts[64 * 128];

  const int tid  = threadIdx.x;
  const int lane = tid & 63;
  const int w    = tid >> 6;
  const int quad = lane >> 4;
  const int l15  = lane & 15;
  const int qt   = (blockIdx.x + 4 * blockIdx.y) & 63;
  const int bh   = blockIdx.y;
  const size_t bh_off = (size_t)bh * 262144;
  const int b = bh >> 3, h = bh & 7;

  // Q fragment lives in registers for the whole kernel (pre-scaled by 0.125)
  bf16x8 aq[2];
  {
    const bf16_t* Qp = Qg + bh_off + (size_t)(qt * 64 + w * 16 + l15) * 64;
    aq[0] = *(const bf16x8*)&Qp[quad * 8];
    aq[1] = *(const bf16x8*)&Qp[32 + quad * 8];
  }

  floatx4 acc_o[4];
  #pragma unroll
  for (int dt = 0; dt < 4; ++dt) acc_o[dt] = (floatx4){0.f, 0.f, 0.f, 0.f};
  float mst = -3.0e38f, lst = 0.f;
  const int gq = qt * 64 + w * 16 + l15;   // this lane's global q row

  const int nkt = (qt >> 1) + 1;
  for (int kt = 0; kt < nkt; ++kt) {
    __syncthreads();
    {
      const bf16_t* Kp = Kgl + bh_off + (size_t)kt * 8192;
      const bf16_t* Vp = Vtg + bh_off + (size_t)kt * 128;
      #pragma unroll
      for (int i = 0; i < 4; ++i) {
        int c = tid + 256 * i;
        int row = c >> 3, colc = c & 7;
        GLDS16(&Kp[row * 64 + ((colc ^ (row & 7)) << 3)], &Ks[c * 8]);
      }
      #pragma unroll
      for (int i = 0; i < 4; ++i) {
        int c = tid + 256 * i;
        int row = c >> 4, colc = c & 15;
        GLDS16(&Vp[(size_t)row * 4096 + ((colc ^ (row & 15)) << 3)], &Vts[c * 8]);
      }
    }
    __syncthreads();

    // ---- S^T = K Q^T : output rows = k (128), cols = q (16 per wave) ----
    floatx4 s[8];
    #pragma unroll
    for (int nt = 0; nt < 8; ++nt) s[nt] = (floatx4){0.f, 0.f, 0.f, 0.f};
    #pragma unroll
    for (int ks = 0; ks < 2; ++ks) {
      #pragma unroll
      for (int nt = 0; nt < 8; ++nt) {
        bf16x8 bk = *(const bf16x8*)&Ks[(nt * 16 + l15) * 64 +
                                        (((ks * 4 + quad) ^ (l15 & 7)) << 3)];
        s[nt] = mfma16(bk, aq[ks], s[nt]);   // A=K (rows=k), B=Q (cols=q)
      }
    }

    // ---- softmax over k: all 32 values in-lane are for q = gq ----
    if (kt == nkt - 1) {      // diagonal tile: mask k > q
      #pragma unroll
      for (int nt = 0; nt < 8; ++nt)
        #pragma unroll
        for (int r = 0; r < 4; ++r)
          if (kt * 128 + nt * 16 + quad * 4 + r > gq) s[nt][r] = -3.0e38f;
    }
    float mx = -3.0e38f;
    #pragma unroll
    for (int nt = 0; nt < 8; ++nt)
      #pragma unroll
      for (int r = 0; r < 4; ++r) mx = fmaxf(mx, s[nt][r]);
    mx = fmaxf(mx, __shfl_xor(mx, 16));
    mx = fmaxf(mx, __shfl_xor(mx, 32));
    float mnew  = fmaxf(mst, mx);
    float alpha = exp2f((mst - mnew) * L2E);
    float sum = 0.f;
    #pragma unroll
    for (int nt = 0; nt < 8; ++nt)
      #pragma unroll
      for (int r = 0; r < 4; ++r) {
        float p = exp2f((s[nt][r] - mnew) * L2E);
        s[nt][r] = p;
        sum += p;
      }
    sum += __shfl_xor(sum, 16);
    sum += __shfl_xor(sum, 32);
    mst = mnew;
    lst = lst * alpha + sum;
    #pragma unroll
    for (int dt = 0; dt < 4; ++dt) acc_o[dt] *= alpha;

    // ---- PV: O^T += V^T P^T. P^T regs are already B-operand k-slots; pair
    //      tiles {2kc,2kc+1} into one K=32 MFMA (k-relabel invariance). ----
    #pragma unroll
    for (int kc = 0; kc < 4; ++kc) {
      bf16x8 pb;
      #pragma unroll
      for (int r = 0; r < 4; ++r) {
        pb[r]     = (bf16_t)s[kc * 2][r];
        pb[r + 4] = (bf16_t)s[kc * 2 + 1][r];
      }
      #pragma unroll
      for (int dt = 0; dt < 4; ++dt) {
        int row = dt * 16 + l15;
        // k0 = kc*32 + quad*4 -> 16B chunk kc*4+(quad>>1), 8B sub quad&1; +16k = +2 chunks
        bf16x4 v0 = *(const bf16x4*)&Vts[row * 128 +
                        (((kc * 4 + (quad >> 1)) ^ l15) << 3) + (quad & 1) * 4];
        bf16x4 v1 = *(const bf16x4*)&Vts[row * 128 +
                        (((kc * 4 + 2 + (quad >> 1)) ^ l15) << 3) + (quad & 1) * 4];
        bf16x8 av;
        #pragma unroll
        for (int r = 0; r < 4; ++r) { av[r] = v0[r]; av[r + 4] = v1[r]; }
        acc_o[dt] = mfma16(av, pb, acc_o[dt]);   // A=V^T (rows=d), B=P^T (cols=q)
      }
    }
  }

  // ---- epilogue: O^T -> LDS transpose (reuse Ks) -> coalesced global ----
  __syncthreads();                       // all waves done reading Ks/Vts
  bf16_t* Ot = Ks;                       // [t][d] 64x64, swizzled 16B chunks
  const float rl = 1.0f / lst;
  const int t_own = w * 16 + l15;
  #pragma unroll
  for (int dt = 0; dt < 4; ++dt) {
    bf16x4 o4;
    #pragma unroll
    for (int r = 0; r < 4; ++r) o4[r] = (bf16_t)(acc_o[dt][r] * rl);
    *(bf16x4*)&Ot[t_own * 64 +
                  (((dt * 2 + (quad >> 1)) ^ (t_own & 7)) << 3) + (quad & 1) * 4] = o4;
  }
  __syncthreads();
  #pragma unroll
  for (int i = 0; i < 2; ++i) {
    int cc = tid + 256 * i;              // 0..511 : 64 t-rows x 8 chunks
    int t = cc >> 3, c = cc & 7;
    bf16x8 o8 = *(const bf16x8*)&Ot[t * 64 + ((c ^ (t & 7)) << 3)];
    *(bf16x8*)&Og[((size_t)b * 4096 + qt * 64 + t) * 512 + h * 64 + c * 8] = o8;
  }
}

// ---------------- launcher ----------------
extern "C" void kernel_launch(void* const* d_in, const int* in_sizes, int n_in,
                              void* d_out, int out_size, void* d_ws, size_t ws_size,
                              hipStream_t stream) {
  const float* x    = (const float*)d_in[0];   // (2,4096,512)
  const float* wqkv = (const float*)d_in[1];   // (1536,512)
  const float* wo   = (const float*)d_in[2];   // (512,512)
  float* out = (float*)d_out;                  // (2,4096,512) fp32

  char* ws = (char*)d_ws;
  bf16_t* xb    = (bf16_t*)(ws);                 //  8 MB
  bf16_t* wqkvb = (bf16_t*)(ws + 8388608);       //  1.5 MB
  bf16_t* wob   = (bf16_t*)(ws + 9961472);       //  0.5 MB
  bf16_t* Qb    = (bf16_t*)(ws + 10485760);      //  8 MB  [bh][t][64], pre-scaled
  bf16_t* Kb    = (bf16_t*)(ws + 18874368);      //  8 MB  [bh][t][64]
  bf16_t* Vtb   = (bf16_t*)(ws + 27262976);      //  8 MB  [bh][64][t]
  bf16_t* Ob    = (bf16_t*)(ws + 35651584);      //  8 MB  (B*T, 512)

  cvt_kernel<<<4096, 256, 0, stream>>>(x,    xb,    1048576);
  cvt_kernel<<<768,  256, 0, stream>>>(wqkv, wqkvb, 196608);
  cvt_kernel<<<256,  256, 0, stream>>>(wo,   wob,   65536);

  gemm_nt<0><<<dim3(64, 12), 256, 0, stream>>>(xb, wqkvb, 8192, 1536, 512,
                                               nullptr, Qb, Kb, Vtb);
  attn_kernel<<<dim3(64, 16), 256, 0, stream>>>(Qb, Kb, Vtb, Ob);
  gemm_nt<1><<<dim3(64, 4), 256, 0, stream>>>(Ob, wob, 8192, 512, 512,
                                              out, nullptr, nullptr, nullptr);
}

// Round 4
// 207.668 us; speedup vs baseline: 1.7514x; 1.0912x over previous
//
#include <hip/hip_runtime.h>
#include <hip/hip_bf16.h>

typedef __bf16 bf16_t;
typedef __bf16 bf16x8 __attribute__((ext_vector_type(8)));
typedef __bf16 bf16x4 __attribute__((ext_vector_type(4)));
typedef float  floatx4 __attribute__((ext_vector_type(4)));

#define L2E 1.44269504088896340736f

static __device__ __forceinline__ floatx4 mfma16(bf16x8 a, bf16x8 b, floatx4 c) {
  return __builtin_amdgcn_mfma_f32_16x16x32_bf16(a, b, c, 0, 0, 0);
}

// async global->LDS, 16B per lane; LDS dest = wave-uniform base + lane*16.
typedef __attribute__((address_space(3))) void lds_vp;
typedef __attribute__((address_space(1))) void glb_vp;
#define GLDS16(g, l) \
  __builtin_amdgcn_global_load_lds((glb_vp*)(g), (lds_vp*)(l), 16, 0, 0)

// ---------------- fp32 -> bf16 convert, 4 elems/thread ----------------
__global__ void cvt_kernel(const float* __restrict__ in, bf16_t* __restrict__ out, int n4) {
  int i = blockIdx.x * blockDim.x + threadIdx.x;
  if (i < n4) {
    float4 v = ((const float4*)in)[i];
    bf16x4 o;
    o[0] = (bf16_t)v.x; o[1] = (bf16_t)v.y; o[2] = (bf16_t)v.z; o[3] = (bf16_t)v.w;
    ((bf16x4*)out)[i] = o;
  }
}

// ---------------- NT GEMM: C(M,N) = A(M,K) * B(N,K)^T ----------------
// EPI==0: qkv scatter -> Q*0.125 [bh][t][64], K [bh][t][64],
//         Vt [bh][64][t'] with t' k-interleaved per 32-group so the attention
//         PV A-fragment {k, k+16} pairs are contiguous 16B chunks.
// EPI==1: plain fp32 store
template <int EPI>
__global__ __launch_bounds__(256) void gemm_nt(
    const bf16_t* __restrict__ A, const bf16_t* __restrict__ B,
    int M, int N, int K, float* __restrict__ Cf,
    bf16_t* __restrict__ Qo, bf16_t* __restrict__ Ko, bf16_t* __restrict__ Vto)
{
  __shared__ __align__(16) bf16_t As[128 * 64];
  __shared__ __align__(16) bf16_t Bs[128 * 64];
  const int tid  = threadIdx.x;
  const int lane = tid & 63;
  const int w    = tid >> 6;
  const int quad = lane >> 4;
  const int l15  = lane & 15;
  const int l7   = lane & 7;
  const int wm   = w & 1;
  const int wn   = w >> 1;

  floatx4 acc[4][4];
  #pragma unroll
  for (int i = 0; i < 4; ++i)
    #pragma unroll
    for (int j = 0; j < 4; ++j)
      acc[i][j] = (floatx4){0.f, 0.f, 0.f, 0.f};

  const bf16_t* Ab = A + (size_t)blockIdx.x * 128 * K;
  const bf16_t* Bb = B + (size_t)blockIdx.y * 128 * K;

  for (int k0 = 0; k0 < K; k0 += 64) {
    __syncthreads();
    #pragma unroll
    for (int i = 0; i < 4; ++i) {
      int c = tid + 256 * i;
      int row = c >> 3, colc = c & 7;
      int gofs = ((colc ^ (row & 7)) << 3);
      GLDS16(&Ab[(size_t)row * K + k0 + gofs], &As[c * 8]);
      GLDS16(&Bb[(size_t)row * K + k0 + gofs], &Bs[c * 8]);
    }
    __syncthreads();
    #pragma unroll
    for (int ks = 0; ks < 2; ++ks) {
      bf16x8 af[4], bfr[4];
      #pragma unroll
      for (int t = 0; t < 4; ++t) {
        af[t]  = *(const bf16x8*)&As[(wm * 64 + t * 16 + l15) * 64 +
                                     (((ks * 4 + quad) ^ l7) << 3)];
        bfr[t] = *(const bf16x8*)&Bs[(wn * 64 + t * 16 + l15) * 64 +
                                     (((ks * 4 + quad) ^ l7) << 3)];
      }
      #pragma unroll
      for (int mt = 0; mt < 4; ++mt)
        #pragma unroll
        for (int nt = 0; nt < 4; ++nt)
          acc[mt][nt] = mfma16(af[mt], bfr[nt], acc[mt][nt]);
    }
  }

  #pragma unroll
  for (int mt = 0; mt < 4; ++mt) {
    #pragma unroll
    for (int nt = 0; nt < 4; ++nt) {
      #pragma unroll
      for (int r = 0; r < 4; ++r) {
        int m = blockIdx.x * 128 + wm * 64 + mt * 16 + quad * 4 + r;
        int n = blockIdx.y * 128 + wn * 64 + nt * 16 + l15;
        float v = acc[mt][nt][r];
        if (EPI == 1) {
          Cf[(size_t)m * N + n] = v;
        } else {
          int b = m >> 12, t = m & 4095;
          int which = n >> 9, h = (n >> 6) & 7, d = n & 63;
          size_t bh = (size_t)(b * 8 + h);
          if (which == 0)
            Qo[bh * 262144 + (size_t)t * 64 + d] = (bf16_t)(v * 0.125f);
          else if (which == 1)
            Ko[bh * 262144 + (size_t)t * 64 + d] = (bf16_t)v;
          else {
            // k-interleave within 32-group: t' = s*8 + h2*4 + r2
            // (s = (t>>2)&3, h2 = (t>>4)&1, r2 = t&3)
            int j = t & 31;
            int tp = (t & ~31) | ((j & 12) << 1) | ((j & 16) >> 2) | (j & 3);
            Vto[bh * 262144 + (size_t)d * 4096 + tp] = (bf16_t)v;
          }
        }
      }
    }
  }
}

// ---------------- causal flash attention, S^T formulation ----------------
// grid (32,16), 512 threads = 8 waves; q-tile 128 rows (wave w owns rows
// w*16..w*16+15, one q per lane-l15). k-tile 128. LDS: Ks 16K + Vts 16K = 32KB
// -> 2 blocks/CU. qt pairing: co-resident blocks (b, b+256) get qt and 31-qt.
// S^T = K Q^T -> in-lane softmax + 2 shfl; P^T feeds PV directly (B-operand);
// l accumulated by a ones-row MFMA; Vt global layout k-interleaved so the PV
// A-fragment is one conflict-free b128.
__global__ __launch_bounds__(512, 4) void attn_kernel(
    const bf16_t* __restrict__ Qg, const bf16_t* __restrict__ Kgl,
    const bf16_t* __restrict__ Vtg, bf16_t* __restrict__ Og)
{
  __shared__ __align__(16) bf16_t Ks[128 * 64];
  __shared__ __align__(16) bf16_t Vts[64 * 128];

  const int tid  = threadIdx.x;
  const int lane = tid & 63;
  const int w    = tid >> 6;            // 0..7
  const int quad = lane >> 4;
  const int l15  = lane & 15;
  const int base = (blockIdx.x + (blockIdx.y & 7) * 4) & 31;
  const int qt   = (blockIdx.y & 8) ? (31 - base) : base;
  const int bh   = blockIdx.y;
  const size_t bh_off = (size_t)bh * 262144;
  const int b = bh >> 3, h = bh & 7;

  // Q fragment in registers for the whole kernel (pre-scaled by 0.125)
  bf16x8 aq[2];
  {
    const bf16_t* Qp = Qg + bh_off + (size_t)(qt * 128 + w * 16 + l15) * 64;
    aq[0] = *(const bf16x8*)&Qp[quad * 8];
    aq[1] = *(const bf16x8*)&Qp[32 + quad * 8];
  }
  bf16x8 ones;
  #pragma unroll
  for (int i = 0; i < 8; ++i) ones[i] = (bf16_t)1.0f;

  floatx4 acc_o[4], acc_l;
  #pragma unroll
  for (int dt = 0; dt < 4; ++dt) acc_o[dt] = (floatx4){0.f, 0.f, 0.f, 0.f};
  acc_l = (floatx4){0.f, 0.f, 0.f, 0.f};
  float mst = -3.0e38f;
  const int gq = qt * 128 + w * 16 + l15;   // this lane's global q row

  const int nkt = qt + 1;
  for (int kt = 0; kt < nkt; ++kt) {
    __syncthreads();
    {
      const bf16_t* Kp = Kgl + bh_off + (size_t)kt * 8192;
      const bf16_t* Vp = Vtg + bh_off + (size_t)kt * 128;
      #pragma unroll
      for (int i = 0; i < 2; ++i) {
        int c = tid + 512 * i;            // 0..1023
        int row = c >> 3, colc = c & 7;
        GLDS16(&Kp[row * 64 + ((colc ^ (row & 7)) << 3)], &Ks[c * 8]);
      }
      #pragma unroll
      for (int i = 0; i < 2; ++i) {
        int c = tid + 512 * i;
        int row = c >> 4, colc = c & 15;
        GLDS16(&Vp[(size_t)row * 4096 + ((colc ^ (row & 15)) << 3)], &Vts[c * 8]);
      }
    }
    __syncthreads();

    // ---- S^T = K Q^T : rows = k (128), cols = q (16 per wave) ----
    floatx4 s[8];
    #pragma unroll
    for (int nt = 0; nt < 8; ++nt) s[nt] = (floatx4){0.f, 0.f, 0.f, 0.f};
    #pragma unroll
    for (int ks = 0; ks < 2; ++ks) {
      #pragma unroll
      for (int nt = 0; nt < 8; ++nt) {
        bf16x8 bk = *(const bf16x8*)&Ks[(nt * 16 + l15) * 64 +
                                        (((ks * 4 + quad) ^ (l15 & 7)) << 3)];
        s[nt] = mfma16(bk, aq[ks], s[nt]);
      }
    }

    // ---- softmax over k (all 32 values in-lane are for q = gq) ----
    if (kt == nkt - 1) {                  // diagonal tile: mask k > q
      #pragma unroll
      for (int nt = 0; nt < 8; ++nt)
        #pragma unroll
        for (int r = 0; r < 4; ++r)
          if (kt * 128 + nt * 16 + quad * 4 + r > gq) s[nt][r] = -3.0e38f;
    }
    float mx = -3.0e38f;
    #pragma unroll
    for (int nt = 0; nt < 8; ++nt)
      #pragma unroll
      for (int r = 0; r < 4; ++r) mx = fmaxf(mx, s[nt][r]);
    mx = fmaxf(mx, __shfl_xor(mx, 16));
    mx = fmaxf(mx, __shfl_xor(mx, 32));
    float mnew  = fmaxf(mst, mx);
    float alpha = exp2f((mst - mnew) * L2E);
    mst = mnew;
    #pragma unroll
    for (int nt = 0; nt < 8; ++nt)
      #pragma unroll
      for (int r = 0; r < 4; ++r)
        s[nt][r] = exp2f((s[nt][r] - mnew) * L2E);
    #pragma unroll
    for (int dt = 0; dt < 4; ++dt) acc_o[dt] *= alpha;
    acc_l *= alpha;

    // ---- PV: O^T += V^T P^T ; l += 1^T P^T (ones-row MFMA) ----
    #pragma unroll
    for (int kc = 0; kc < 4; ++kc) {
      bf16x8 pb;
      #pragma unroll
      for (int r = 0; r < 4; ++r) {
        pb[r]     = (bf16_t)s[kc * 2][r];
        pb[r + 4] = (bf16_t)s[kc * 2 + 1][r];
      }
      acc_l = mfma16(ones, pb, acc_l);
      #pragma unroll
      for (int dt = 0; dt < 4; ++dt) {
        int row = dt * 16 + l15;
        bf16x8 av = *(const bf16x8*)&Vts[row * 128 +
                                         (((kc * 4 + quad) ^ l15) << 3)];
        acc_o[dt] = mfma16(av, pb, acc_o[dt]);
      }
    }
  }

  // ---- epilogue: O^T -> LDS transpose (reuse Ks) -> coalesced global ----
  __syncthreads();
  bf16_t* Ot = Ks;                        // [t][d] 128x64, swizzled chunks
  const float rl = 1.0f / acc_l[0];
  const int t_own = w * 16 + l15;
  #pragma unroll
  for (int dt = 0; dt < 4; ++dt) {
    bf16x4 o4;
    #pragma unroll
    for (int r = 0; r < 4; ++r) o4[r] = (bf16_t)(acc_o[dt][r] * rl);
    *(bf16x4*)&Ot[t_own * 64 +
                  (((dt * 2 + (quad >> 1)) ^ (t_own & 7)) << 3) + (quad & 1) * 4] = o4;
  }
  __syncthreads();
  #pragma unroll
  for (int i = 0; i < 2; ++i) {
    int cc = tid + 512 * i;               // 0..1023 : 128 t-rows x 8 chunks
    int t = cc >> 3, c = cc & 7;
    bf16x8 o8 = *(const bf16x8*)&Ot[t * 64 + ((c ^ (t & 7)) << 3)];
    *(bf16x8*)&Og[((size_t)b * 4096 + qt * 128 + t) * 512 + h * 64 + c * 8] = o8;
  }
}

// ---------------- launcher ----------------
extern "C" void kernel_launch(void* const* d_in, const int* in_sizes, int n_in,
                              void* d_out, int out_size, void* d_ws, size_t ws_size,
                              hipStream_t stream) {
  const float* x    = (const float*)d_in[0];   // (2,4096,512)
  const float* wqkv = (const float*)d_in[1];   // (1536,512)
  const float* wo   = (const float*)d_in[2];   // (512,512)
  float* out = (float*)d_out;                  // (2,4096,512) fp32

  char* ws = (char*)d_ws;
  bf16_t* xb    = (bf16_t*)(ws);                 //  8 MB
  bf16_t* wqkvb = (bf16_t*)(ws + 8388608);       //  1.5 MB
  bf16_t* wob   = (bf16_t*)(ws + 9961472);       //  0.5 MB
  bf16_t* Qb    = (bf16_t*)(ws + 10485760);      //  8 MB  [bh][t][64], pre-scaled
  bf16_t* Kb    = (bf16_t*)(ws + 18874368);      //  8 MB  [bh][t][64]
  bf16_t* Vtb   = (bf16_t*)(ws + 27262976);      //  8 MB  [bh][64][t'], k-interleaved
  bf16_t* Ob    = (bf16_t*)(ws + 35651584);      //  8 MB  (B*T, 512)

  cvt_kernel<<<4096, 256, 0, stream>>>(x,    xb,    1048576);
  cvt_kernel<<<768,  256, 0, stream>>>(wqkv, wqkvb, 196608);
  cvt_kernel<<<256,  256, 0, stream>>>(wo,   wob,   65536);

  gemm_nt<0><<<dim3(64, 12), 256, 0, stream>>>(xb, wqkvb, 8192, 1536, 512,
                                               nullptr, Qb, Kb, Vtb);
  attn_kernel<<<dim3(32, 16), 512, 0, stream>>>(Qb, Kb, Vtb, Ob);
  gemm_nt<1><<<dim3(64, 4), 256, 0, stream>>>(Ob, wob, 8192, 512, 512,
                                              out, nullptr, nullptr, nullptr);
}